// Round 2
// baseline (3118.049 us; speedup 1.0000x reference)
//
#include <hip/hip_runtime.h>
#include <math.h>

#define D_MODEL 512
#define D_INNER 1024
#define DT_RANK 32
#define D_STATE 16
#define D_CONV 4
#define NB_LAYERS 3
#define BATCH 64
#define SEQ 201
#define CITY 200
#define M_ROWS (BATCH * SEQ)   // 12864, multiple of 64
#define EPS 1e-5f

__device__ __forceinline__ float sigmoidf_(float x) { return 1.f / (1.f + __expf(-x)); }

// ---------------- embed: h[m][d] = x[m][0]*W[d][0] + x[m][1]*W[d][1] + b[d] ----------------
__global__ __launch_bounds__(256) void k_embed(const float* __restrict__ x,
                                               const float* __restrict__ W,
                                               const float* __restrict__ b,
                                               float* __restrict__ h) {
  int idx = blockIdx.x * 256 + threadIdx.x;
  if (idx >= M_ROWS * D_MODEL) return;
  int d = idx & (D_MODEL - 1);
  int m = idx >> 9;
  float x0 = x[m * 2 + 0], x1 = x[m * 2 + 1];
  h[idx] = fmaf(x0, W[d * 2 + 0], fmaf(x1, W[d * 2 + 1], b[d]));
}

// ---------------- fused residual add + LayerNorm / RMSNorm ----------------
// resid = h + (addRes ? resid : 0); out = norm(resid)*w + b
// one wave (64 lanes) per row of 512. Safe for out==h (regs loaded first, per-lane cols).
__global__ __launch_bounds__(256) void k_resid_norm(const float* __restrict__ h,
                                                    float* __restrict__ resid,
                                                    float* __restrict__ out,
                                                    const float* __restrict__ w,
                                                    const float* __restrict__ b,
                                                    int addRes, int mode) {
  int row = blockIdx.x * 4 + (threadIdx.x >> 6);
  int lane = threadIdx.x & 63;
  if (row >= M_ROWS) return;
  const float* hp = h + (size_t)row * D_MODEL;
  float* rp = resid + (size_t)row * D_MODEL;
  float* op = out + (size_t)row * D_MODEL;
  float v[8];
#pragma unroll
  for (int j = 0; j < 8; ++j) {
    float t = hp[j * 64 + lane];
    if (addRes) t += rp[j * 64 + lane];
    v[j] = t;
    rp[j * 64 + lane] = t;
  }
  if (mode == 0) {  // layernorm
    float s = 0.f;
#pragma unroll
    for (int j = 0; j < 8; ++j) s += v[j];
#pragma unroll
    for (int o = 1; o < 64; o <<= 1) s += __shfl_xor(s, o);
    float mu = s * (1.f / D_MODEL);
    float vs = 0.f;
#pragma unroll
    for (int j = 0; j < 8; ++j) { float d0 = v[j] - mu; vs += d0 * d0; }
#pragma unroll
    for (int o = 1; o < 64; o <<= 1) vs += __shfl_xor(vs, o);
    float rstd = rsqrtf(vs * (1.f / D_MODEL) + EPS);
#pragma unroll
    for (int j = 0; j < 8; ++j) {
      int c = j * 64 + lane;
      op[c] = (v[j] - mu) * rstd * w[c] + b[c];
    }
  } else {  // rmsnorm
    float s = 0.f;
#pragma unroll
    for (int j = 0; j < 8; ++j) s += v[j] * v[j];
#pragma unroll
    for (int o = 1; o < 64; o <<= 1) s += __shfl_xor(s, o);
    float rstd = rsqrtf(s * (1.f / D_MODEL) + EPS);
#pragma unroll
    for (int j = 0; j < 8; ++j) {
      int c = j * 64 + lane;
      op[c] = v[j] * rstd * w[c] + b[c];
    }
  }
}

// ---------------- generic tiled fp32 GEMM: C[M,N] = A[M,K(lda)] @ W[N,K]^T (+bias)(+act) ----
// TILE=64, KSTEP=16, 256 threads, 4x4 per thread. M must be a multiple of 64.
#define TILE 64
#define KSTEP 16
#define LDSPAD 68

template <int ACT>  // 0 = none, 1 = softplus
__global__ __launch_bounds__(256) void k_gemm_tn(const float* __restrict__ A, int lda,
                                                 const float* __restrict__ W,
                                                 const float* __restrict__ bias,
                                                 float* __restrict__ C, int ldc,
                                                 int N, int K) {
  __shared__ float As[KSTEP][LDSPAD];
  __shared__ float Ws[KSTEP][LDSPAD];
  int bm = blockIdx.y * TILE;
  int bn = blockIdx.x * TILE;
  int tid = threadIdx.x;
  int lj = tid & 15;          // k within tile
  int li = (tid >> 4) * 4;    // row base within tile
  int tn = (tid & 15) * 4;    // output col base
  int tm = (tid >> 4) * 4;    // output row base
  float acc[4][4] = {};
  for (int k0 = 0; k0 < K; k0 += KSTEP) {
    int k = k0 + lj;
#pragma unroll
    for (int r = 0; r < 4; ++r) {
      int m = bm + li + r;
      As[lj][li + r] = (k < K) ? A[(size_t)m * lda + k] : 0.f;
      int n = bn + li + r;
      Ws[lj][li + r] = (k < K && n < N) ? W[(size_t)n * K + k] : 0.f;
    }
    __syncthreads();
#pragma unroll
    for (int kk = 0; kk < KSTEP; ++kk) {
      float4 a4 = *(const float4*)&As[kk][tm];
      float4 w4 = *(const float4*)&Ws[kk][tn];
      float a[4] = {a4.x, a4.y, a4.z, a4.w};
      float w[4] = {w4.x, w4.y, w4.z, w4.w};
#pragma unroll
      for (int r = 0; r < 4; ++r)
#pragma unroll
        for (int c = 0; c < 4; ++c) acc[r][c] = fmaf(a[r], w[c], acc[r][c]);
    }
    __syncthreads();
  }
#pragma unroll
  for (int r = 0; r < 4; ++r) {
    int m = bm + tm + r;
#pragma unroll
    for (int c = 0; c < 4; ++c) {
      int n = bn + tn + c;
      if (n < N) {
        float v = acc[r][c];
        if (bias) v += bias[n];
        if (ACT == 1) v = (v > 20.f) ? v : log1pf(__expf(v));
        C[(size_t)m * ldc + n] = v;
      }
    }
  }
}

// ---------------- depthwise causal conv (width 4) + bias + SiLU ----------------
// u[m][d] = silu( sum_k cw[d][k] * xc[b, l-3+k, d] + cb[d] ), xc = first 1024 cols of xz
__global__ __launch_bounds__(256) void k_conv_silu(const float* __restrict__ xz,
                                                   const float* __restrict__ cw,
                                                   const float* __restrict__ cb,
                                                   float* __restrict__ u) {
  int idx = blockIdx.x * 256 + threadIdx.x;
  if (idx >= M_ROWS * D_INNER) return;
  int d = idx & (D_INNER - 1);
  int m = idx >> 10;
  int l = m % SEQ;
  float acc = cb[d];
#pragma unroll
  for (int k = 0; k < D_CONV; ++k) {
    int ls = l - (D_CONV - 1) + k;
    if (ls >= 0) acc = fmaf(cw[d * D_CONV + k], xz[(size_t)(m - (D_CONV - 1) + k) * 2048 + d], acc);
  }
  u[idx] = acc * sigmoidf_(acc);
}

// ---------------- selective scan, fused with D-skip and y *= silu(z) ----------------
// one thread per (b, d); 16 states in registers; writes final y in place over u
// dt lives in cols [0,1024) of the 2048-stride xz buffer (overwrote dead xc); z in [1024,2048)
__global__ __launch_bounds__(256) void k_scan(const float* __restrict__ xz_dtz,
                                              float* __restrict__ u,
                                              const float* __restrict__ xdbl,
                                              const float* __restrict__ A_log,
                                              const float* __restrict__ Dv) {
  int d = blockIdx.y * 256 + threadIdx.x;
  int b = blockIdx.x;
  float Areg[D_STATE];
#pragma unroll
  for (int n = 0; n < D_STATE; ++n) Areg[n] = -__expf(A_log[d * D_STATE + n]);
  float Dd = Dv[d];
  float hst[D_STATE];
#pragma unroll
  for (int n = 0; n < D_STATE; ++n) hst[n] = 0.f;
  size_t row0 = (size_t)b * SEQ;
  for (int t = 0; t < SEQ; ++t) {
    size_t m = row0 + t;
    float dtv = xz_dtz[m * 2048 + d];
    float uv = u[m * D_INNER + d];
    float zv = xz_dtz[m * 2048 + 1024 + d];
    const float* xd = xdbl + m * 64;
    float du = dtv * uv;
    float y = 0.f;
#pragma unroll
    for (int n = 0; n < D_STATE; ++n) {
      float Bn = xd[DT_RANK + n];
      float Cn = xd[DT_RANK + D_STATE + n];
      hst[n] = fmaf(__expf(dtv * Areg[n]), hst[n], du * Bn);
      y = fmaf(hst[n], Cn, y);
    }
    y = fmaf(Dd, uv, y);
    y = y * (zv * sigmoidf_(zv));
    u[m * D_INNER + d] = y;
  }
}

extern "C" void kernel_launch(void* const* d_in, const int* in_sizes, int n_in,
                              void* d_out, int out_size, void* d_ws, size_t ws_size,
                              hipStream_t stream) {
  const float* x        = (const float*)d_in[0];
  // d_in[1] = city_count (unused)
  const float* embed_W  = (const float*)d_in[2];
  const float* embed_b  = (const float*)d_in[3];
  const float* norm_w   = (const float*)d_in[4];
  const float* norm_b   = (const float*)d_in[5];
  const float* in_W     = (const float*)d_in[6];
  const float* conv_w   = (const float*)d_in[7];
  const float* conv_b   = (const float*)d_in[8];
  const float* xproj_W  = (const float*)d_in[9];
  const float* dtproj_W = (const float*)d_in[10];
  const float* dtproj_b = (const float*)d_in[11];
  const float* A_log    = (const float*)d_in[12];
  const float* Dskip    = (const float*)d_in[13];
  const float* out_W    = (const float*)d_in[14];
  const float* normf_w  = (const float*)d_in[15];
  const float* normf_b  = (const float*)d_in[16];
  const float* head_W   = (const float*)d_in[17];
  float* out = (float*)d_out;

  // workspace layout: M*(512 res + 512 h/hn + 2048 xz(dt|z) + 1024 u + 64 xdbl) = 204 MiB
  size_t need = (size_t)M_ROWS * 4160 * sizeof(float);
  if (ws_size < need) return;  // diagnosable clean failure instead of GPU fault

  float* ws = (float*)d_ws;
  float* buf_res  = ws;                                   // M*512
  float* buf_h    = buf_res  + (size_t)M_ROWS * 512;      // M*512 (h, then hn in-place)
  float* buf_xz   = buf_h    + (size_t)M_ROWS * 512;      // M*2048 (xc|z, later dt|z)
  float* buf_u    = buf_xz   + (size_t)M_ROWS * 2048;     // M*1024 (u, then y)
  float* buf_xdbl = buf_u    + (size_t)M_ROWS * 1024;     // M*64

  dim3 blk(256);

  // embed
  k_embed<<<(M_ROWS * D_MODEL + 255) / 256, blk, 0, stream>>>(x, embed_W, embed_b, buf_h);

  for (int i = 0; i < NB_LAYERS; ++i) {
    // residual update + layernorm (hn written in place over h)
    k_resid_norm<<<(M_ROWS + 3) / 4, blk, 0, stream>>>(
        buf_h, buf_res, buf_h, norm_w + i * D_MODEL, norm_b + i * D_MODEL, i > 0 ? 1 : 0, 0);

    // in_proj: xz = hn @ in_W^T   (M, 2048)
    k_gemm_tn<0><<<dim3(2048 / TILE, M_ROWS / TILE), blk, 0, stream>>>(
        buf_h, D_MODEL, in_W + (size_t)i * 2048 * D_MODEL, nullptr, buf_xz, 2048, 2048, D_MODEL);

    // conv + silu -> u
    k_conv_silu<<<(M_ROWS * D_INNER + 255) / 256, blk, 0, stream>>>(
        buf_xz, conv_w + (size_t)i * D_INNER * D_CONV, conv_b + (size_t)i * D_INNER, buf_u);

    // x_proj: xdbl = u @ xproj_W^T   (M, 64)
    k_gemm_tn<0><<<dim3(1, M_ROWS / TILE), blk, 0, stream>>>(
        buf_u, D_INNER, xproj_W + (size_t)i * 64 * D_INNER, nullptr, buf_xdbl, 64, 64, D_INNER);

    // dt_proj + softplus -> cols [0,1024) of xz (xc is dead after conv); ldc=2048
    k_gemm_tn<1><<<dim3(D_INNER / TILE, M_ROWS / TILE), blk, 0, stream>>>(
        buf_xdbl, 64, dtproj_W + (size_t)i * D_INNER * DT_RANK, dtproj_b + (size_t)i * D_INNER,
        buf_xz, 2048, D_INNER, DT_RANK);

    // selective scan (writes final gated y over buf_u)
    k_scan<<<dim3(BATCH, D_INNER / 256), blk, 0, stream>>>(
        buf_xz, buf_u, buf_xdbl, A_log + (size_t)i * D_INNER * D_STATE,
        Dskip + (size_t)i * D_INNER);

    // out_proj: h = y @ out_W^T   (M, 512)
    k_gemm_tn<0><<<dim3(D_MODEL / TILE, M_ROWS / TILE), blk, 0, stream>>>(
        buf_u, D_INNER, out_W + (size_t)i * D_MODEL * D_INNER, nullptr, buf_h, D_MODEL,
        D_MODEL, D_INNER);
  }

  // final residual + rmsnorm (in place over h)
  k_resid_norm<<<(M_ROWS + 3) / 4, blk, 0, stream>>>(
      buf_h, buf_res, buf_h, normf_w, normf_b, 1, 1);

  // head: logits = xf @ head_W^T   (M, 200)
  k_gemm_tn<0><<<dim3((CITY + TILE - 1) / TILE, M_ROWS / TILE), blk, 0, stream>>>(
      buf_h, D_MODEL, head_W, nullptr, out, CITY, CITY, D_MODEL);
}

// Round 3
// 1515.242 us; speedup vs baseline: 2.0578x; 2.0578x over previous
//
#include <hip/hip_runtime.h>
#include <math.h>

#define D_MODEL 512
#define D_INNER 1024
#define DT_RANK 32
#define D_STATE 16
#define D_CONV 4
#define NB_LAYERS 3
#define BATCH 64
#define SEQ 201
#define CITY 200
#define M_ROWS (BATCH * SEQ)   // 12864 = 64*201
#define M_PAD 12928            // 128*101, for 128-row MFMA tiles
#define EPS 1e-5f

typedef __attribute__((ext_vector_type(8))) short short8;
typedef __attribute__((ext_vector_type(4))) float f32x4;

__device__ __forceinline__ float sigmoidf_(float x) { return 1.f / (1.f + __expf(-x)); }

__device__ __forceinline__ unsigned short f2b(float f) {  // RNE fp32->bf16
  union { float f; unsigned int u; } v; v.f = f;
  unsigned int r = (v.u + 0x7fff + ((v.u >> 16) & 1)) >> 16;
  return (unsigned short)r;
}

__device__ __forceinline__ void gload_lds16(const void* g, void* l) {
  __builtin_amdgcn_global_load_lds(
      (const __attribute__((address_space(1))) void*)g,
      (__attribute__((address_space(3))) void*)l, 16, 0, 0);
}

// ---------------- fp32 -> bf16 bulk convert ----------------
__global__ __launch_bounds__(256) void k_f2b(const float* __restrict__ in,
                                             unsigned short* __restrict__ out, int n) {
  int i = blockIdx.x * 256 + threadIdx.x;
  if (i < n) out[i] = f2b(in[i]);
}

// ---------------- embed ----------------
__global__ __launch_bounds__(256) void k_embed(const float* __restrict__ x,
                                               const float* __restrict__ W,
                                               const float* __restrict__ b,
                                               float* __restrict__ h) {
  int idx = blockIdx.x * 256 + threadIdx.x;
  if (idx >= M_ROWS * D_MODEL) return;
  int d = idx & (D_MODEL - 1);
  int m = idx >> 9;
  float x0 = x[m * 2 + 0], x1 = x[m * 2 + 1];
  h[idx] = fmaf(x0, W[d * 2 + 0], fmaf(x1, W[d * 2 + 1], b[d]));
}

// ---------------- fused residual add + LayerNorm / RMSNorm ----------------
// resid = h + (addRes ? resid : 0); norm -> fp32 out (if non-null) and/or bf16 out_b
__global__ __launch_bounds__(256) void k_resid_norm(const float* __restrict__ h,
                                                    float* __restrict__ resid,
                                                    float* __restrict__ out,
                                                    unsigned short* __restrict__ out_b,
                                                    const float* __restrict__ w,
                                                    const float* __restrict__ b,
                                                    int addRes, int mode) {
  int row = blockIdx.x * 4 + (threadIdx.x >> 6);
  int lane = threadIdx.x & 63;
  if (row >= M_ROWS) return;
  const float* hp = h + (size_t)row * D_MODEL;
  float* rp = resid + (size_t)row * D_MODEL;
  float v[8];
#pragma unroll
  for (int j = 0; j < 8; ++j) {
    float t = hp[j * 64 + lane];
    if (addRes) t += rp[j * 64 + lane];
    v[j] = t;
    rp[j * 64 + lane] = t;
  }
  float mu = 0.f, rstd;
  if (mode == 0) {
    float s = 0.f;
#pragma unroll
    for (int j = 0; j < 8; ++j) s += v[j];
#pragma unroll
    for (int o = 1; o < 64; o <<= 1) s += __shfl_xor(s, o);
    mu = s * (1.f / D_MODEL);
    float vs = 0.f;
#pragma unroll
    for (int j = 0; j < 8; ++j) { float d0 = v[j] - mu; vs += d0 * d0; }
#pragma unroll
    for (int o = 1; o < 64; o <<= 1) vs += __shfl_xor(vs, o);
    rstd = rsqrtf(vs * (1.f / D_MODEL) + EPS);
  } else {
    float s = 0.f;
#pragma unroll
    for (int j = 0; j < 8; ++j) s += v[j] * v[j];
#pragma unroll
    for (int o = 1; o < 64; o <<= 1) s += __shfl_xor(s, o);
    rstd = rsqrtf(s * (1.f / D_MODEL) + EPS);
  }
#pragma unroll
  for (int j = 0; j < 8; ++j) {
    int c = j * 64 + lane;
    float o = (v[j] - mu) * rstd * w[c] + b[c];
    if (out) out[(size_t)row * D_MODEL + c] = o;
    if (out_b) out_b[(size_t)row * D_MODEL + c] = f2b(o);
  }
}

// ---------------- bf16 MFMA GEMM: C[M,N](fp32,ldc) = A[M,K]bf16 @ B[N,K]bf16^T ------------
// BM=BN=128, BK=64, 256 threads (4 waves, 2x2 of 64x64). N%128==0, K%64==0.
// A must be padded to 128-row multiple (reads); C store guarded by m<M.
__global__ __launch_bounds__(256) void k_gemm_mfma(const unsigned short* __restrict__ A,
                                                   const unsigned short* __restrict__ B,
                                                   float* __restrict__ C, int ldc,
                                                   int M, int N, int K) {
  __shared__ unsigned short lA[128 * 64];
  __shared__ unsigned short lB[128 * 64];
  int tid = threadIdx.x;
  int wave = tid >> 6, lane = tid & 63;
  int bm = blockIdx.y * 128, bn = blockIdx.x * 128;
  int wm = (wave >> 1) * 64, wn = (wave & 1) * 64;
  f32x4 acc[4][4] = {};

  for (int k0 = 0; k0 < K; k0 += 64) {
#pragma unroll
    for (int i = 0; i < 4; ++i) {
      int e = (i * 256 + tid) * 8;   // flat bf16 element in [128][64] tile
      int r = e >> 6, c = e & 63;
      gload_lds16(A + (size_t)(bm + r) * K + k0 + c, &lA[e]);
      gload_lds16(B + (size_t)(bn + r) * K + k0 + c, &lB[e]);
    }
    __syncthreads();
#pragma unroll
    for (int ks = 0; ks < 2; ++ks) {
      int koff = ks * 32 + (lane >> 4) * 8;
      short8 a[4], b[4];
#pragma unroll
      for (int i = 0; i < 4; ++i)
        a[i] = *(const short8*)&lA[(wm + i * 16 + (lane & 15)) * 64 + koff];
#pragma unroll
      for (int j = 0; j < 4; ++j)
        b[j] = *(const short8*)&lB[(wn + j * 16 + (lane & 15)) * 64 + koff];
#pragma unroll
      for (int i = 0; i < 4; ++i)
#pragma unroll
        for (int j = 0; j < 4; ++j)
          acc[i][j] = __builtin_amdgcn_mfma_f32_16x16x32_bf16(a[i], b[j], acc[i][j], 0, 0, 0);
    }
    __syncthreads();
  }
  // C/D layout: col = lane&15, row = (lane>>4)*4 + reg   [m89-verified]
#pragma unroll
  for (int i = 0; i < 4; ++i) {
    int row0 = bm + wm + i * 16 + (lane >> 4) * 4;
#pragma unroll
    for (int j = 0; j < 4; ++j) {
      int col = bn + wn + j * 16 + (lane & 15);
#pragma unroll
      for (int r = 0; r < 4; ++r) {
        int m = row0 + r;
        if (m < M) C[(size_t)m * ldc + col] = acc[i][j][r];
      }
    }
  }
}

// ---------------- fp32 tiled GEMM (kept for small/sensitive GEMMs) ----------------
#define TILE 64
#define KSTEP 16
#define LDSPAD 68

template <int ACT>  // 0 = none, 1 = softplus
__global__ __launch_bounds__(256) void k_gemm_tn(const float* __restrict__ A, int lda,
                                                 const float* __restrict__ W,
                                                 const float* __restrict__ bias,
                                                 float* __restrict__ C, int ldc,
                                                 int N, int K) {
  __shared__ float As[KSTEP][LDSPAD];
  __shared__ float Ws[KSTEP][LDSPAD];
  int bm = blockIdx.y * TILE;
  int bn = blockIdx.x * TILE;
  int tid = threadIdx.x;
  int lj = tid & 15;
  int li = (tid >> 4) * 4;
  int tn = (tid & 15) * 4;
  int tm = (tid >> 4) * 4;
  float acc[4][4] = {};
  for (int k0 = 0; k0 < K; k0 += KSTEP) {
    int k = k0 + lj;
#pragma unroll
    for (int r = 0; r < 4; ++r) {
      int m = bm + li + r;
      As[lj][li + r] = (k < K) ? A[(size_t)m * lda + k] : 0.f;
      int n = bn + li + r;
      Ws[lj][li + r] = (k < K && n < N) ? W[(size_t)n * K + k] : 0.f;
    }
    __syncthreads();
#pragma unroll
    for (int kk = 0; kk < KSTEP; ++kk) {
      float4 a4 = *(const float4*)&As[kk][tm];
      float4 w4 = *(const float4*)&Ws[kk][tn];
      float a[4] = {a4.x, a4.y, a4.z, a4.w};
      float w[4] = {w4.x, w4.y, w4.z, w4.w};
#pragma unroll
      for (int r = 0; r < 4; ++r)
#pragma unroll
        for (int c = 0; c < 4; ++c) acc[r][c] = fmaf(a[r], w[c], acc[r][c]);
    }
    __syncthreads();
  }
#pragma unroll
  for (int r = 0; r < 4; ++r) {
    int m = bm + tm + r;
#pragma unroll
    for (int c = 0; c < 4; ++c) {
      int n = bn + tn + c;
      if (n < N) {
        float v = acc[r][c];
        if (bias) v += bias[n];
        if (ACT == 1) v = (v > 20.f) ? v : log1pf(__expf(v));
        C[(size_t)m * ldc + n] = v;
      }
    }
  }
}

// ---------------- depthwise causal conv (width 4) + bias + SiLU ----------------
__global__ __launch_bounds__(256) void k_conv_silu(const float* __restrict__ xz,
                                                   const float* __restrict__ cw,
                                                   const float* __restrict__ cb,
                                                   float* __restrict__ u) {
  int idx = blockIdx.x * 256 + threadIdx.x;
  if (idx >= M_ROWS * D_INNER) return;
  int d = idx & (D_INNER - 1);
  int m = idx >> 10;
  int l = m % SEQ;
  float acc = cb[d];
#pragma unroll
  for (int k = 0; k < D_CONV; ++k) {
    int ls = l - (D_CONV - 1) + k;
    if (ls >= 0) acc = fmaf(cw[d * D_CONV + k], xz[(size_t)(m - (D_CONV - 1) + k) * 2048 + d], acc);
  }
  u[idx] = acc * sigmoidf_(acc);
}

// ---------------- selective scan fused with D-skip + z-gate; writes y as bf16 ----------------
// dt in cols [0,1024) of the 2048-stride xz buffer; z in [1024,2048)
__global__ __launch_bounds__(256) void k_scan(const float* __restrict__ xz_dtz,
                                              const float* __restrict__ u,
                                              const float* __restrict__ xdbl,
                                              const float* __restrict__ A_log,
                                              const float* __restrict__ Dv,
                                              unsigned short* __restrict__ yb) {
  int d = blockIdx.y * 256 + threadIdx.x;
  int b = blockIdx.x;
  float Areg[D_STATE];
#pragma unroll
  for (int n = 0; n < D_STATE; ++n) Areg[n] = -__expf(A_log[d * D_STATE + n]);
  float Dd = Dv[d];
  float hst[D_STATE];
#pragma unroll
  for (int n = 0; n < D_STATE; ++n) hst[n] = 0.f;
  size_t row0 = (size_t)b * SEQ;
  for (int t = 0; t < SEQ; ++t) {
    size_t m = row0 + t;
    float dtv = xz_dtz[m * 2048 + d];
    float uv = u[m * D_INNER + d];
    float zv = xz_dtz[m * 2048 + 1024 + d];
    const float* xd = xdbl + m * 64;
    float du = dtv * uv;
    float y = 0.f;
#pragma unroll
    for (int n = 0; n < D_STATE; ++n) {
      float Bn = xd[DT_RANK + n];
      float Cn = xd[DT_RANK + D_STATE + n];
      hst[n] = fmaf(__expf(dtv * Areg[n]), hst[n], du * Bn);
      y = fmaf(hst[n], Cn, y);
    }
    y = fmaf(Dd, uv, y);
    y = y * (zv * sigmoidf_(zv));
    yb[m * D_INNER + d] = f2b(y);
  }
}

extern "C" void kernel_launch(void* const* d_in, const int* in_sizes, int n_in,
                              void* d_out, int out_size, void* d_ws, size_t ws_size,
                              hipStream_t stream) {
  const float* x        = (const float*)d_in[0];
  const float* embed_W  = (const float*)d_in[2];
  const float* embed_b  = (const float*)d_in[3];
  const float* norm_w   = (const float*)d_in[4];
  const float* norm_b   = (const float*)d_in[5];
  const float* in_W     = (const float*)d_in[6];
  const float* conv_w   = (const float*)d_in[7];
  const float* conv_b   = (const float*)d_in[8];
  const float* xproj_W  = (const float*)d_in[9];
  const float* dtproj_W = (const float*)d_in[10];
  const float* dtproj_b = (const float*)d_in[11];
  const float* A_log    = (const float*)d_in[12];
  const float* Dskip    = (const float*)d_in[13];
  const float* out_W    = (const float*)d_in[14];
  const float* normf_w  = (const float*)d_in[15];
  const float* normf_b  = (const float*)d_in[16];
  const float* head_W   = (const float*)d_in[17];
  float* out = (float*)d_out;

  // fp32: res 512 + h 512 + xz 2048 + u 1024 + xdbl 64 = 4160*M floats (204.2 MiB)
  // bf16: yb/hnb union M_PAD*1024 (25.3 MiB) + weights 1.57M elems (3.0 MiB)  => ~232.5 MiB
  size_t f32_elems = (size_t)M_ROWS * 4160;
  size_t need = f32_elems * 4 + (size_t)M_PAD * 1024 * 2 + (size_t)(2048 * 512 + 512 * 1024) * 2;
  if (ws_size < need) return;

  float* ws = (float*)d_ws;
  float* buf_res  = ws;                                   // M*512
  float* buf_h    = buf_res  + (size_t)M_ROWS * 512;      // M*512
  float* buf_xz   = buf_h    + (size_t)M_ROWS * 512;      // M*2048 (xc|z, later dt|z)
  float* buf_u    = buf_xz   + (size_t)M_ROWS * 2048;     // M*1024
  float* buf_xdbl = buf_u    + (size_t)M_ROWS * 1024;     // M*64
  unsigned short* buf_yb  = (unsigned short*)(buf_xdbl + (size_t)M_ROWS * 64); // M_PAD*1024 bf16
  unsigned short* buf_hnb = buf_yb;                       // M_PAD*512 bf16 (alias: hn dead before scan writes y)
  unsigned short* buf_wib = buf_yb + (size_t)M_PAD * 1024;   // 2048*512 bf16 (in_W layer)
  unsigned short* buf_wob = buf_wib + (size_t)2048 * 512;    // 512*1024 bf16 (out_W layer)

  dim3 blk(256);

  // zero the M..M_PAD pad rows of the bf16 activation buffers (finite garbage would also
  // be harmless — discarded by m<M store guard — but zeros are deterministic)
  hipMemsetAsync(buf_hnb + (size_t)M_ROWS * 512, 0, (size_t)(M_PAD - M_ROWS) * 512 * 2, stream);
  hipMemsetAsync(buf_yb + (size_t)M_ROWS * 1024, 0, (size_t)(M_PAD - M_ROWS) * 1024 * 2, stream);

  k_embed<<<(M_ROWS * D_MODEL + 255) / 256, blk, 0, stream>>>(x, embed_W, embed_b, buf_h);

  for (int i = 0; i < NB_LAYERS; ++i) {
    // weight -> bf16 (per layer)
    k_f2b<<<(2048 * 512 + 255) / 256, blk, 0, stream>>>(
        in_W + (size_t)i * 2048 * D_MODEL, buf_wib, 2048 * 512);
    k_f2b<<<(512 * 1024 + 255) / 256, blk, 0, stream>>>(
        out_W + (size_t)i * D_MODEL * D_INNER, buf_wob, 512 * 1024);

    // residual update + layernorm -> hn (bf16 only)
    k_resid_norm<<<(M_ROWS + 3) / 4, blk, 0, stream>>>(
        buf_h, buf_res, nullptr, buf_hnb, norm_w + i * D_MODEL, norm_b + i * D_MODEL,
        i > 0 ? 1 : 0, 0);

    // in_proj (bf16 MFMA): xz = hn @ in_W^T   (M, 2048)
    k_gemm_mfma<<<dim3(2048 / 128, M_PAD / 128), blk, 0, stream>>>(
        buf_hnb, buf_wib, buf_xz, 2048, M_ROWS, 2048, 512);

    // conv + silu -> u (fp32)
    k_conv_silu<<<(M_ROWS * D_INNER + 255) / 256, blk, 0, stream>>>(
        buf_xz, conv_w + (size_t)i * D_INNER * D_CONV, conv_b + (size_t)i * D_INNER, buf_u);

    // x_proj (fp32): xdbl = u @ xproj_W^T   (M, 64)
    k_gemm_tn<0><<<dim3(1, M_ROWS / TILE), blk, 0, stream>>>(
        buf_u, D_INNER, xproj_W + (size_t)i * 64 * D_INNER, nullptr, buf_xdbl, 64, 64, D_INNER);

    // dt_proj + softplus (fp32) -> cols [0,1024) of xz; ldc=2048
    k_gemm_tn<1><<<dim3(D_INNER / TILE, M_ROWS / TILE), blk, 0, stream>>>(
        buf_xdbl, 64, dtproj_W + (size_t)i * D_INNER * DT_RANK, dtproj_b + (size_t)i * D_INNER,
        buf_xz, 2048, D_INNER, DT_RANK);

    // selective scan -> y (bf16, overwrites hn region; hn is dead)
    k_scan<<<dim3(BATCH, D_INNER / 256), blk, 0, stream>>>(
        buf_xz, buf_u, buf_xdbl, A_log + (size_t)i * D_INNER * D_STATE,
        Dskip + (size_t)i * D_INNER, buf_yb);

    // out_proj (bf16 MFMA): h = y @ out_W^T   (M, 512)
    k_gemm_mfma<<<dim3(512 / 128, M_PAD / 128), blk, 0, stream>>>(
        buf_yb, buf_wob, buf_h, 512, M_ROWS, 512, 1024);
  }

  // final residual + rmsnorm (fp32, in place over h)
  k_resid_norm<<<(M_ROWS + 3) / 4, blk, 0, stream>>>(
      buf_h, buf_res, buf_h, nullptr, normf_w, normf_b, 1, 1);

  // head (fp32): logits = xf @ head_W^T   (M, 200)
  k_gemm_tn<0><<<dim3((CITY + TILE - 1) / TILE, M_ROWS / TILE), blk, 0, stream>>>(
      buf_h, D_MODEL, head_W, nullptr, out, CITY, CITY, D_MODEL);
}

// Round 4
// 1399.219 us; speedup vs baseline: 2.2284x; 1.0829x over previous
//
#include <hip/hip_runtime.h>
#include <math.h>

#define D_MODEL 512
#define D_INNER 1024
#define DT_RANK 32
#define D_STATE 16
#define D_CONV 4
#define NB_LAYERS 3
#define BATCH 64
#define SEQ 201
#define CITY 200
#define M_ROWS (BATCH * SEQ)   // 12864 = 64*201
#define M_PAD 12928            // 128*101, for 128-row MFMA tiles
#define EPS 1e-5f

typedef __attribute__((ext_vector_type(8))) short short8;
typedef __attribute__((ext_vector_type(4))) float f32x4;

__device__ __forceinline__ float sigmoidf_(float x) { return 1.f / (1.f + __expf(-x)); }

__device__ __forceinline__ unsigned short f2b(float f) {  // RNE fp32->bf16
  union { float f; unsigned int u; } v; v.f = f;
  unsigned int r = (v.u + 0x7fff + ((v.u >> 16) & 1)) >> 16;
  return (unsigned short)r;
}

__device__ __forceinline__ void gload_lds16(const void* g, void* l) {
  __builtin_amdgcn_global_load_lds(
      (const __attribute__((address_space(1))) void*)g,
      (__attribute__((address_space(3))) void*)l, 16, 0, 0);
}

// ---------------- fp32 -> bf16 bulk convert (zero-pad tail to n_total) ----------------
__global__ __launch_bounds__(256) void k_f2b(const float* __restrict__ in,
                                             unsigned short* __restrict__ out,
                                             int n, int n_total) {
  int i = blockIdx.x * 256 + threadIdx.x;
  if (i < n) out[i] = f2b(in[i]);
  else if (i < n_total) out[i] = 0;
}

// ---------------- embed ----------------
__global__ __launch_bounds__(256) void k_embed(const float* __restrict__ x,
                                               const float* __restrict__ W,
                                               const float* __restrict__ b,
                                               float* __restrict__ h) {
  int idx = blockIdx.x * 256 + threadIdx.x;
  if (idx >= M_ROWS * D_MODEL) return;
  int d = idx & (D_MODEL - 1);
  int m = idx >> 9;
  float x0 = x[m * 2 + 0], x1 = x[m * 2 + 1];
  h[idx] = fmaf(x0, W[d * 2 + 0], fmaf(x1, W[d * 2 + 1], b[d]));
}

// ---------------- fused residual add + LayerNorm / RMSNorm ----------------
__global__ __launch_bounds__(256) void k_resid_norm(const float* __restrict__ h,
                                                    float* __restrict__ resid,
                                                    float* __restrict__ out,
                                                    unsigned short* __restrict__ out_b,
                                                    const float* __restrict__ w,
                                                    const float* __restrict__ b,
                                                    int addRes, int mode) {
  int row = blockIdx.x * 4 + (threadIdx.x >> 6);
  int lane = threadIdx.x & 63;
  if (row >= M_ROWS) return;
  const float* hp = h + (size_t)row * D_MODEL;
  float* rp = resid + (size_t)row * D_MODEL;
  float v[8];
#pragma unroll
  for (int j = 0; j < 8; ++j) {
    float t = hp[j * 64 + lane];
    if (addRes) t += rp[j * 64 + lane];
    v[j] = t;
    rp[j * 64 + lane] = t;
  }
  float mu = 0.f, rstd;
  if (mode == 0) {
    float s = 0.f;
#pragma unroll
    for (int j = 0; j < 8; ++j) s += v[j];
#pragma unroll
    for (int o = 1; o < 64; o <<= 1) s += __shfl_xor(s, o);
    mu = s * (1.f / D_MODEL);
    float vs = 0.f;
#pragma unroll
    for (int j = 0; j < 8; ++j) { float d0 = v[j] - mu; vs += d0 * d0; }
#pragma unroll
    for (int o = 1; o < 64; o <<= 1) vs += __shfl_xor(vs, o);
    rstd = rsqrtf(vs * (1.f / D_MODEL) + EPS);
  } else {
    float s = 0.f;
#pragma unroll
    for (int j = 0; j < 8; ++j) s += v[j] * v[j];
#pragma unroll
    for (int o = 1; o < 64; o <<= 1) s += __shfl_xor(s, o);
    rstd = rsqrtf(s * (1.f / D_MODEL) + EPS);
  }
#pragma unroll
  for (int j = 0; j < 8; ++j) {
    int c = j * 64 + lane;
    float o = (v[j] - mu) * rstd * w[c] + b[c];
    if (out) out[(size_t)row * D_MODEL + c] = o;
    if (out_b) out_b[(size_t)row * D_MODEL + c] = f2b(o);
  }
}

// ---------------- bf16 MFMA GEMM: C[M,Nout](fp32,ldc) = A[M,K]bf16 @ B[N,K]bf16^T ----------
// BM=BN=128, BK=64, 256 threads (4 waves, 2x2 of 64x64). N%128==0, K%64==0.
// A padded to 128-row multiple; store guarded by m<M && col<Nout.
__global__ __launch_bounds__(256) void k_gemm_mfma(const unsigned short* __restrict__ A,
                                                   const unsigned short* __restrict__ B,
                                                   float* __restrict__ C, int ldc,
                                                   int M, int Nout, int K) {
  __shared__ unsigned short lA[128 * 64];
  __shared__ unsigned short lB[128 * 64];
  int tid = threadIdx.x;
  int wave = tid >> 6, lane = tid & 63;
  int bm = blockIdx.y * 128, bn = blockIdx.x * 128;
  int wm = (wave >> 1) * 64, wn = (wave & 1) * 64;
  f32x4 acc[4][4] = {};

  for (int k0 = 0; k0 < K; k0 += 64) {
#pragma unroll
    for (int i = 0; i < 4; ++i) {
      int e = (i * 256 + tid) * 8;   // flat bf16 element in [128][64] tile
      int r = e >> 6, c = e & 63;
      gload_lds16(A + (size_t)(bm + r) * K + k0 + c, &lA[e]);
      gload_lds16(B + (size_t)(bn + r) * K + k0 + c, &lB[e]);
    }
    __syncthreads();
#pragma unroll
    for (int ks = 0; ks < 2; ++ks) {
      int koff = ks * 32 + (lane >> 4) * 8;
      short8 a[4], b[4];
#pragma unroll
      for (int i = 0; i < 4; ++i)
        a[i] = *(const short8*)&lA[(wm + i * 16 + (lane & 15)) * 64 + koff];
#pragma unroll
      for (int j = 0; j < 4; ++j)
        b[j] = *(const short8*)&lB[(wn + j * 16 + (lane & 15)) * 64 + koff];
#pragma unroll
      for (int i = 0; i < 4; ++i)
#pragma unroll
        for (int j = 0; j < 4; ++j)
          acc[i][j] = __builtin_amdgcn_mfma_f32_16x16x32_bf16(a[i], b[j], acc[i][j], 0, 0, 0);
    }
    __syncthreads();
  }
  // C/D layout: col = lane&15, row = (lane>>4)*4 + reg   [m89-verified]
#pragma unroll
  for (int i = 0; i < 4; ++i) {
    int row0 = bm + wm + i * 16 + (lane >> 4) * 4;
#pragma unroll
    for (int j = 0; j < 4; ++j) {
      int col = bn + wn + j * 16 + (lane & 15);
#pragma unroll
      for (int r = 0; r < 4; ++r) {
        int m = row0 + r;
        if (m < M && col < Nout) C[(size_t)m * ldc + col] = acc[i][j][r];
      }
    }
  }
}

// ---------------- fp32 tiled GEMM (kept for dt_proj) ----------------
#define TILE 64
#define KSTEP 16
#define LDSPAD 68

template <int ACT>  // 0 = none, 1 = softplus
__global__ __launch_bounds__(256) void k_gemm_tn(const float* __restrict__ A, int lda,
                                                 const float* __restrict__ W,
                                                 const float* __restrict__ bias,
                                                 float* __restrict__ C, int ldc,
                                                 int N, int K) {
  __shared__ float As[KSTEP][LDSPAD];
  __shared__ float Ws[KSTEP][LDSPAD];
  int bm = blockIdx.y * TILE;
  int bn = blockIdx.x * TILE;
  int tid = threadIdx.x;
  int lj = tid & 15;
  int li = (tid >> 4) * 4;
  int tn = (tid & 15) * 4;
  int tm = (tid >> 4) * 4;
  float acc[4][4] = {};
  for (int k0 = 0; k0 < K; k0 += KSTEP) {
    int k = k0 + lj;
#pragma unroll
    for (int r = 0; r < 4; ++r) {
      int m = bm + li + r;
      As[lj][li + r] = (k < K) ? A[(size_t)m * lda + k] : 0.f;
      int n = bn + li + r;
      Ws[lj][li + r] = (k < K && n < N) ? W[(size_t)n * K + k] : 0.f;
    }
    __syncthreads();
#pragma unroll
    for (int kk = 0; kk < KSTEP; ++kk) {
      float4 a4 = *(const float4*)&As[kk][tm];
      float4 w4 = *(const float4*)&Ws[kk][tn];
      float a[4] = {a4.x, a4.y, a4.z, a4.w};
      float w[4] = {w4.x, w4.y, w4.z, w4.w};
#pragma unroll
      for (int r = 0; r < 4; ++r)
#pragma unroll
        for (int c = 0; c < 4; ++c) acc[r][c] = fmaf(a[r], w[c], acc[r][c]);
    }
    __syncthreads();
  }
#pragma unroll
  for (int r = 0; r < 4; ++r) {
    int m = bm + tm + r;
#pragma unroll
    for (int c = 0; c < 4; ++c) {
      int n = bn + tn + c;
      if (n < N) {
        float v = acc[r][c];
        if (bias) v += bias[n];
        if (ACT == 1) v = (v > 20.f) ? v : log1pf(__expf(v));
        C[(size_t)m * ldc + n] = v;
      }
    }
  }
}

// ---------------- x_proj: xdbl[M,64] = u[M,1024] @ W[64,1024]^T ----------------
// 16 rows x 64 cols per block -> 804 blocks. u staged in LDS; W from global (L1-resident).
#define XP_TM 16
__global__ __launch_bounds__(256) void k_xproj(const float* __restrict__ u,
                                               const float* __restrict__ W,
                                               float* __restrict__ xdbl) {
  __shared__ float lu[XP_TM][128];
  int m0 = blockIdx.x * XP_TM;
  int tid = threadIdx.x;
  int col = tid & 63;
  int rg = tid >> 6;  // 0..3 (wave index)
  float acc[4] = {0.f, 0.f, 0.f, 0.f};
  for (int k0 = 0; k0 < 1024; k0 += 128) {
#pragma unroll
    for (int i = 0; i < 2; ++i) {
      int e = (i * 256 + tid) * 4;  // 0..4095 floats in [16][128]
      int r = e >> 7, c = e & 127;
      *(float4*)&lu[r][c] = *(const float4*)&u[(size_t)(m0 + r) * 1024 + k0 + c];
    }
    __syncthreads();
#pragma unroll
    for (int k = 0; k < 128; k += 4) {
      float4 w4 = *(const float4*)&W[(size_t)col * 1024 + k0 + k];
#pragma unroll
      for (int i = 0; i < 4; ++i) {
        float4 u4 = *(const float4*)&lu[rg * 4 + i][k];  // wave-broadcast, conflict-free
        acc[i] = fmaf(u4.x, w4.x, acc[i]);
        acc[i] = fmaf(u4.y, w4.y, acc[i]);
        acc[i] = fmaf(u4.z, w4.z, acc[i]);
        acc[i] = fmaf(u4.w, w4.w, acc[i]);
      }
    }
    __syncthreads();
  }
#pragma unroll
  for (int i = 0; i < 4; ++i)
    xdbl[(size_t)(m0 + rg * 4 + i) * 64 + col] = acc[i];
}

// ---------------- depthwise causal conv (width 4) + bias + SiLU ----------------
__global__ __launch_bounds__(256) void k_conv_silu(const float* __restrict__ xz,
                                                   const float* __restrict__ cw,
                                                   const float* __restrict__ cb,
                                                   float* __restrict__ u) {
  int idx = blockIdx.x * 256 + threadIdx.x;
  if (idx >= M_ROWS * D_INNER) return;
  int d = idx & (D_INNER - 1);
  int m = idx >> 10;
  int l = m % SEQ;
  float acc = cb[d];
#pragma unroll
  for (int k = 0; k < D_CONV; ++k) {
    int ls = l - (D_CONV - 1) + k;
    if (ls >= 0) acc = fmaf(cw[d * D_CONV + k], xz[(size_t)(m - (D_CONV - 1) + k) * 2048 + d], acc);
  }
  u[idx] = acc * sigmoidf_(acc);
}

// ---------------- selective scan fused with D-skip + z-gate; writes y as bf16 ----------------
__global__ __launch_bounds__(256) void k_scan(const float* __restrict__ xz_dtz,
                                              const float* __restrict__ u,
                                              const float* __restrict__ xdbl,
                                              const float* __restrict__ A_log,
                                              const float* __restrict__ Dv,
                                              unsigned short* __restrict__ yb) {
  int d = blockIdx.y * 256 + threadIdx.x;
  int b = blockIdx.x;
  float Areg[D_STATE];
#pragma unroll
  for (int n = 0; n < D_STATE; ++n) Areg[n] = -__expf(A_log[d * D_STATE + n]);
  float Dd = Dv[d];
  float hst[D_STATE];
#pragma unroll
  for (int n = 0; n < D_STATE; ++n) hst[n] = 0.f;
  size_t row0 = (size_t)b * SEQ;
  for (int t = 0; t < SEQ; ++t) {
    size_t m = row0 + t;
    float dtv = xz_dtz[m * 2048 + d];
    float uv = u[m * D_INNER + d];
    float zv = xz_dtz[m * 2048 + 1024 + d];
    const float* xd = xdbl + m * 64;
    float du = dtv * uv;
    float y = 0.f;
#pragma unroll
    for (int n = 0; n < D_STATE; ++n) {
      float Bn = xd[DT_RANK + n];
      float Cn = xd[DT_RANK + D_STATE + n];
      hst[n] = fmaf(__expf(dtv * Areg[n]), hst[n], du * Bn);
      y = fmaf(hst[n], Cn, y);
    }
    y = fmaf(Dd, uv, y);
    y = y * (zv * sigmoidf_(zv));
    yb[m * D_INNER + d] = f2b(y);
  }
}

extern "C" void kernel_launch(void* const* d_in, const int* in_sizes, int n_in,
                              void* d_out, int out_size, void* d_ws, size_t ws_size,
                              hipStream_t stream) {
  const float* x        = (const float*)d_in[0];
  const float* embed_W  = (const float*)d_in[2];
  const float* embed_b  = (const float*)d_in[3];
  const float* norm_w   = (const float*)d_in[4];
  const float* norm_b   = (const float*)d_in[5];
  const float* in_W     = (const float*)d_in[6];
  const float* conv_w   = (const float*)d_in[7];
  const float* conv_b   = (const float*)d_in[8];
  const float* xproj_W  = (const float*)d_in[9];
  const float* dtproj_W = (const float*)d_in[10];
  const float* dtproj_b = (const float*)d_in[11];
  const float* A_log    = (const float*)d_in[12];
  const float* Dskip    = (const float*)d_in[13];
  const float* out_W    = (const float*)d_in[14];
  const float* normf_w  = (const float*)d_in[15];
  const float* normf_b  = (const float*)d_in[16];
  const float* head_W   = (const float*)d_in[17];
  float* out = (float*)d_out;

  size_t f32_elems = (size_t)M_ROWS * 4160;
  size_t need = f32_elems * 4 + (size_t)M_PAD * 1024 * 2 + (size_t)(2048 * 512 + 512 * 1024) * 2;
  if (ws_size < need) return;

  float* ws = (float*)d_ws;
  float* buf_res  = ws;                                   // M*512
  float* buf_h    = buf_res  + (size_t)M_ROWS * 512;      // M*512
  float* buf_xz   = buf_h    + (size_t)M_ROWS * 512;      // M*2048 (xc|z, later dt|z)
  float* buf_u    = buf_xz   + (size_t)M_ROWS * 2048;     // M*1024
  float* buf_xdbl = buf_u    + (size_t)M_ROWS * 1024;     // M*64
  unsigned short* buf_yb  = (unsigned short*)(buf_xdbl + (size_t)M_ROWS * 64); // M_PAD*1024 bf16
  unsigned short* buf_hnb = buf_yb;                       // M_PAD*512 bf16 alias (sequencing-safe)
  unsigned short* buf_wib = buf_yb + (size_t)M_PAD * 1024;   // 2048*512 bf16 (in_W layer; head_W after loop)
  unsigned short* buf_wob = buf_wib + (size_t)2048 * 512;    // 512*1024 bf16 (out_W layer)

  dim3 blk(256);

  k_embed<<<(M_ROWS * D_MODEL + 255) / 256, blk, 0, stream>>>(x, embed_W, embed_b, buf_h);

  for (int i = 0; i < NB_LAYERS; ++i) {
    // weights -> bf16 (per layer)
    k_f2b<<<(2048 * 512 + 255) / 256, blk, 0, stream>>>(
        in_W + (size_t)i * 2048 * D_MODEL, buf_wib, 2048 * 512, 2048 * 512);
    k_f2b<<<(512 * 1024 + 255) / 256, blk, 0, stream>>>(
        out_W + (size_t)i * D_MODEL * D_INNER, buf_wob, 512 * 1024, 512 * 1024);

    // residual update + layernorm -> hn (bf16)
    k_resid_norm<<<(M_ROWS + 3) / 4, blk, 0, stream>>>(
        buf_h, buf_res, nullptr, buf_hnb, norm_w + i * D_MODEL, norm_b + i * D_MODEL,
        i > 0 ? 1 : 0, 0);

    // in_proj (bf16 MFMA): xz = hn @ in_W^T   (M, 2048)
    k_gemm_mfma<<<dim3(2048 / 128, M_PAD / 128), blk, 0, stream>>>(
        buf_hnb, buf_wib, buf_xz, 2048, M_ROWS, 2048, 512);

    // conv + silu -> u (fp32)
    k_conv_silu<<<(M_ROWS * D_INNER + 255) / 256, blk, 0, stream>>>(
        buf_xz, conv_w + (size_t)i * D_INNER * D_CONV, conv_b + (size_t)i * D_INNER, buf_u);

    // x_proj (dedicated high-occupancy kernel): xdbl = u @ xproj_W^T   (M, 64)
    k_xproj<<<M_ROWS / XP_TM, blk, 0, stream>>>(
        buf_u, xproj_W + (size_t)i * 64 * D_INNER, buf_xdbl);

    // dt_proj + softplus (fp32) -> cols [0,1024) of xz; ldc=2048
    k_gemm_tn<1><<<dim3(D_INNER / TILE, M_ROWS / TILE), blk, 0, stream>>>(
        buf_xdbl, 64, dtproj_W + (size_t)i * D_INNER * DT_RANK, dtproj_b + (size_t)i * D_INNER,
        buf_xz, 2048, D_INNER, DT_RANK);

    // selective scan -> y (bf16, overwrites hn region; hn is dead)
    k_scan<<<dim3(BATCH, D_INNER / 256), blk, 0, stream>>>(
        buf_xz, buf_u, buf_xdbl, A_log + (size_t)i * D_INNER * D_STATE,
        Dskip + (size_t)i * D_INNER, buf_yb);

    // out_proj (bf16 MFMA): h = y @ out_W^T   (M, 512)
    k_gemm_mfma<<<dim3(512 / 128, M_PAD / 128), blk, 0, stream>>>(
        buf_yb, buf_wob, buf_h, 512, M_ROWS, 512, 1024);
  }

  // final residual + rmsnorm -> xf (bf16, over hnb region; y dead)
  k_resid_norm<<<(M_ROWS + 3) / 4, blk, 0, stream>>>(
      buf_h, buf_res, nullptr, buf_hnb, normf_w, normf_b, 1, 1);

  // head_W -> bf16 padded to 256 rows (reuse in_W bf16 buffer — dead after last in_proj)
  k_f2b<<<(256 * 512 + 255) / 256, blk, 0, stream>>>(head_W, buf_wib, CITY * 512, 256 * 512);

  // head (bf16 MFMA): logits = xf @ head_W^T   (M, 200), N padded to 256
  k_gemm_mfma<<<dim3(256 / 128, M_PAD / 128), blk, 0, stream>>>(
      buf_hnb, buf_wib, out, CITY, M_ROWS, CITY, 512);
}

// Round 5
// 1106.385 us; speedup vs baseline: 2.8182x; 1.2647x over previous
//
#include <hip/hip_runtime.h>
#include <math.h>

#define D_MODEL 512
#define D_INNER 1024
#define DT_RANK 32
#define D_STATE 16
#define D_CONV 4
#define NB_LAYERS 3
#define BATCH 64
#define SEQ 201
#define CITY 200
#define M_ROWS (BATCH * SEQ)   // 12864 = 64*201
#define M_PAD 12928            // 128*101, for 128-row MFMA tiles
#define EPS 1e-5f

typedef __attribute__((ext_vector_type(8))) short short8;
typedef __attribute__((ext_vector_type(4))) float f32x4;

__device__ __forceinline__ float sigmoidf_(float x) { return 1.f / (1.f + __expf(-x)); }

__device__ __forceinline__ unsigned short f2b(float f) {  // RNE fp32->bf16
  union { float f; unsigned int u; } v; v.f = f;
  unsigned int r = (v.u + 0x7fff + ((v.u >> 16) & 1)) >> 16;
  return (unsigned short)r;
}
__device__ __forceinline__ float b2f(unsigned short h) {
  union { unsigned int u; float f; } v; v.u = ((unsigned int)h) << 16; return v.f;
}

__device__ __forceinline__ void gload_lds16(const void* g, void* l) {
  __builtin_amdgcn_global_load_lds(
      (const __attribute__((address_space(1))) void*)g,
      (__attribute__((address_space(3))) void*)l, 16, 0, 0);
}

// ---------------- fp32 -> bf16 bulk convert (zero-pad tail to n_total) ----------------
__global__ __launch_bounds__(256) void k_f2b(const float* __restrict__ in,
                                             unsigned short* __restrict__ out,
                                             int n, int n_total) {
  int i = blockIdx.x * 256 + threadIdx.x;
  if (i < n) out[i] = f2b(in[i]);
  else if (i < n_total) out[i] = 0;
}

// ---------------- embed ----------------
__global__ __launch_bounds__(256) void k_embed(const float* __restrict__ x,
                                               const float* __restrict__ W,
                                               const float* __restrict__ b,
                                               float* __restrict__ h) {
  int idx = blockIdx.x * 256 + threadIdx.x;
  if (idx >= M_ROWS * D_MODEL) return;
  int d = idx & (D_MODEL - 1);
  int m = idx >> 9;
  float x0 = x[m * 2 + 0], x1 = x[m * 2 + 1];
  h[idx] = fmaf(x0, W[d * 2 + 0], fmaf(x1, W[d * 2 + 1], b[d]));
}

// ---------------- fused residual add + LayerNorm / RMSNorm ----------------
__global__ __launch_bounds__(256) void k_resid_norm(const float* __restrict__ h,
                                                    float* __restrict__ resid,
                                                    float* __restrict__ out,
                                                    unsigned short* __restrict__ out_b,
                                                    const float* __restrict__ w,
                                                    const float* __restrict__ b,
                                                    int addRes, int mode) {
  int row = blockIdx.x * 4 + (threadIdx.x >> 6);
  int lane = threadIdx.x & 63;
  if (row >= M_ROWS) return;
  const float* hp = h + (size_t)row * D_MODEL;
  float* rp = resid + (size_t)row * D_MODEL;
  float v[8];
#pragma unroll
  for (int j = 0; j < 8; ++j) {
    float t = hp[j * 64 + lane];
    if (addRes) t += rp[j * 64 + lane];
    v[j] = t;
    rp[j * 64 + lane] = t;
  }
  float mu = 0.f, rstd;
  if (mode == 0) {
    float s = 0.f;
#pragma unroll
    for (int j = 0; j < 8; ++j) s += v[j];
#pragma unroll
    for (int o = 1; o < 64; o <<= 1) s += __shfl_xor(s, o);
    mu = s * (1.f / D_MODEL);
    float vs = 0.f;
#pragma unroll
    for (int j = 0; j < 8; ++j) { float d0 = v[j] - mu; vs += d0 * d0; }
#pragma unroll
    for (int o = 1; o < 64; o <<= 1) vs += __shfl_xor(vs, o);
    rstd = rsqrtf(vs * (1.f / D_MODEL) + EPS);
  } else {
    float s = 0.f;
#pragma unroll
    for (int j = 0; j < 8; ++j) s += v[j] * v[j];
#pragma unroll
    for (int o = 1; o < 64; o <<= 1) s += __shfl_xor(s, o);
    rstd = rsqrtf(s * (1.f / D_MODEL) + EPS);
  }
#pragma unroll
  for (int j = 0; j < 8; ++j) {
    int c = j * 64 + lane;
    float o = (v[j] - mu) * rstd * w[c] + b[c];
    if (out) out[(size_t)row * D_MODEL + c] = o;
    if (out_b) out_b[(size_t)row * D_MODEL + c] = f2b(o);
  }
}

// ---------------- bf16 MFMA GEMM: C[M,Nout](fp32,ldc) = A[M,K]bf16 @ B[N,K]bf16^T ----------
// BM=BN=128, BK=64, 256 threads (4 waves, 2x2 of 64x64). Ngrid%128==0, K%64==0.
// A padded to 128-row multiple; store guarded by m<M && col<Nout.
__global__ __launch_bounds__(256) void k_gemm_mfma(const unsigned short* __restrict__ A,
                                                   const unsigned short* __restrict__ B,
                                                   float* __restrict__ C, int ldc,
                                                   int M, int Nout, int K) {
  __shared__ unsigned short lA[128 * 64];
  __shared__ unsigned short lB[128 * 64];
  int tid = threadIdx.x;
  int wave = tid >> 6, lane = tid & 63;
  int bm = blockIdx.y * 128, bn = blockIdx.x * 128;
  int wm = (wave >> 1) * 64, wn = (wave & 1) * 64;
  f32x4 acc[4][4] = {};

  for (int k0 = 0; k0 < K; k0 += 64) {
#pragma unroll
    for (int i = 0; i < 4; ++i) {
      int e = (i * 256 + tid) * 8;   // flat bf16 element in [128][64] tile
      int r = e >> 6, c = e & 63;
      gload_lds16(A + (size_t)(bm + r) * K + k0 + c, &lA[e]);
      gload_lds16(B + (size_t)(bn + r) * K + k0 + c, &lB[e]);
    }
    __syncthreads();
#pragma unroll
    for (int ks = 0; ks < 2; ++ks) {
      int koff = ks * 32 + (lane >> 4) * 8;
      short8 a[4], b[4];
#pragma unroll
      for (int i = 0; i < 4; ++i)
        a[i] = *(const short8*)&lA[(wm + i * 16 + (lane & 15)) * 64 + koff];
#pragma unroll
      for (int j = 0; j < 4; ++j)
        b[j] = *(const short8*)&lB[(wn + j * 16 + (lane & 15)) * 64 + koff];
#pragma unroll
      for (int i = 0; i < 4; ++i)
#pragma unroll
        for (int j = 0; j < 4; ++j)
          acc[i][j] = __builtin_amdgcn_mfma_f32_16x16x32_bf16(a[i], b[j], acc[i][j], 0, 0, 0);
    }
    __syncthreads();
  }
  // C/D layout: col = lane&15, row = (lane>>4)*4 + reg   [m89-verified]
#pragma unroll
  for (int i = 0; i < 4; ++i) {
    int row0 = bm + wm + i * 16 + (lane >> 4) * 4;
#pragma unroll
    for (int j = 0; j < 4; ++j) {
      int col = bn + wn + j * 16 + (lane & 15);
#pragma unroll
      for (int r = 0; r < 4; ++r) {
        int m = row0 + r;
        if (m < M && col < Nout) C[(size_t)m * ldc + col] = acc[i][j][r];
      }
    }
  }
}

// ---------------- fp32 tiled GEMM (kept for dt_proj) ----------------
#define TILE 64
#define KSTEP 16
#define LDSPAD 68

template <int ACT>  // 0 = none, 1 = softplus
__global__ __launch_bounds__(256) void k_gemm_tn(const float* __restrict__ A, int lda,
                                                 const float* __restrict__ W,
                                                 const float* __restrict__ bias,
                                                 float* __restrict__ C, int ldc,
                                                 int N, int K) {
  __shared__ float As[KSTEP][LDSPAD];
  __shared__ float Ws[KSTEP][LDSPAD];
  int bm = blockIdx.y * TILE;
  int bn = blockIdx.x * TILE;
  int tid = threadIdx.x;
  int lj = tid & 15;
  int li = (tid >> 4) * 4;
  int tn = (tid & 15) * 4;
  int tm = (tid >> 4) * 4;
  float acc[4][4] = {};
  for (int k0 = 0; k0 < K; k0 += KSTEP) {
    int k = k0 + lj;
#pragma unroll
    for (int r = 0; r < 4; ++r) {
      int m = bm + li + r;
      As[lj][li + r] = (k < K) ? A[(size_t)m * lda + k] : 0.f;
      int n = bn + li + r;
      Ws[lj][li + r] = (k < K && n < N) ? W[(size_t)n * K + k] : 0.f;
    }
    __syncthreads();
#pragma unroll
    for (int kk = 0; kk < KSTEP; ++kk) {
      float4 a4 = *(const float4*)&As[kk][tm];
      float4 w4 = *(const float4*)&Ws[kk][tn];
      float a[4] = {a4.x, a4.y, a4.z, a4.w};
      float w[4] = {w4.x, w4.y, w4.z, w4.w};
#pragma unroll
      for (int r = 0; r < 4; ++r)
#pragma unroll
        for (int c = 0; c < 4; ++c) acc[r][c] = fmaf(a[r], w[c], acc[r][c]);
    }
    __syncthreads();
  }
#pragma unroll
  for (int r = 0; r < 4; ++r) {
    int m = bm + tm + r;
#pragma unroll
    for (int c = 0; c < 4; ++c) {
      int n = bn + tn + c;
      if (n < N) {
        float v = acc[r][c];
        if (bias) v += bias[n];
        if (ACT == 1) v = (v > 20.f) ? v : log1pf(__expf(v));
        C[(size_t)m * ldc + n] = v;
      }
    }
  }
}

// ---------------- depthwise causal conv (width 4) + bias + SiLU -> bf16 u ----------------
__global__ __launch_bounds__(256) void k_conv_silu(const float* __restrict__ xz,
                                                   const float* __restrict__ cw,
                                                   const float* __restrict__ cb,
                                                   unsigned short* __restrict__ ub) {
  int idx = blockIdx.x * 256 + threadIdx.x;
  if (idx >= M_ROWS * D_INNER) return;
  int d = idx & (D_INNER - 1);
  int m = idx >> 10;
  int l = m % SEQ;
  float acc = cb[d];
#pragma unroll
  for (int k = 0; k < D_CONV; ++k) {
    int ls = l - (D_CONV - 1) + k;
    if (ls >= 0) acc = fmaf(cw[d * D_CONV + k], xz[(size_t)(m - (D_CONV - 1) + k) * 2048 + d], acc);
  }
  ub[idx] = f2b(acc * sigmoidf_(acc));
}

// ---------------- selective scan fused with D-skip + z-gate; u bf16 in, y bf16 out --------
__global__ __launch_bounds__(256) void k_scan(const float* __restrict__ xz_dtz,
                                              const unsigned short* __restrict__ ub,
                                              const float* __restrict__ xdbl,
                                              const float* __restrict__ A_log,
                                              const float* __restrict__ Dv,
                                              unsigned short* __restrict__ yb) {
  int d = blockIdx.y * 256 + threadIdx.x;
  int b = blockIdx.x;
  float Areg[D_STATE];
#pragma unroll
  for (int n = 0; n < D_STATE; ++n) Areg[n] = -__expf(A_log[d * D_STATE + n]);
  float Dd = Dv[d];
  float hst[D_STATE];
#pragma unroll
  for (int n = 0; n < D_STATE; ++n) hst[n] = 0.f;
  size_t row0 = (size_t)b * SEQ;
  for (int t = 0; t < SEQ; ++t) {
    size_t m = row0 + t;
    float dtv = xz_dtz[m * 2048 + d];
    float uv = b2f(ub[m * D_INNER + d]);
    float zv = xz_dtz[m * 2048 + 1024 + d];
    const float* xd = xdbl + m * 64;
    float du = dtv * uv;
    float y = 0.f;
#pragma unroll
    for (int n = 0; n < D_STATE; ++n) {
      float Bn = xd[DT_RANK + n];
      float Cn = xd[DT_RANK + D_STATE + n];
      hst[n] = fmaf(__expf(dtv * Areg[n]), hst[n], du * Bn);
      y = fmaf(hst[n], Cn, y);
    }
    y = fmaf(Dd, uv, y);
    y = y * (zv * sigmoidf_(zv));
    yb[m * D_INNER + d] = f2b(y);
  }
}

extern "C" void kernel_launch(void* const* d_in, const int* in_sizes, int n_in,
                              void* d_out, int out_size, void* d_ws, size_t ws_size,
                              hipStream_t stream) {
  const float* x        = (const float*)d_in[0];
  const float* embed_W  = (const float*)d_in[2];
  const float* embed_b  = (const float*)d_in[3];
  const float* norm_w   = (const float*)d_in[4];
  const float* norm_b   = (const float*)d_in[5];
  const float* in_W     = (const float*)d_in[6];
  const float* conv_w   = (const float*)d_in[7];
  const float* conv_b   = (const float*)d_in[8];
  const float* xproj_W  = (const float*)d_in[9];
  const float* dtproj_W = (const float*)d_in[10];
  const float* dtproj_b = (const float*)d_in[11];
  const float* A_log    = (const float*)d_in[12];
  const float* Dskip    = (const float*)d_in[13];
  const float* out_W    = (const float*)d_in[14];
  const float* normf_w  = (const float*)d_in[15];
  const float* normf_b  = (const float*)d_in[16];
  const float* head_W   = (const float*)d_in[17];
  float* out = (float*)d_out;

  // fp32: res 512 + h 512 + xz 2048 + xdbl 64 = 3136*M (157.4 MiB)
  // bf16: ub M_PAD*1024 + yb M_PAD*1024 + wib 2048*512 + wob 512*1024 + wxb 128*1024
  size_t f32_elems = (size_t)M_ROWS * 3136;
  size_t bf16_elems = (size_t)M_PAD * 2048 + 2048 * 512 + 512 * 1024 + 128 * 1024;
  size_t need = f32_elems * 4 + bf16_elems * 2;
  if (ws_size < need) return;

  float* ws = (float*)d_ws;
  float* buf_res  = ws;                                   // M*512
  float* buf_h    = buf_res  + (size_t)M_ROWS * 512;      // M*512
  float* buf_xz   = buf_h    + (size_t)M_ROWS * 512;      // M*2048 (xc|z, later dt|z)
  float* buf_xdbl = buf_xz   + (size_t)M_ROWS * 2048;     // M*64
  unsigned short* buf_ub  = (unsigned short*)(buf_xdbl + (size_t)M_ROWS * 64); // M_PAD*1024
  unsigned short* buf_yb  = buf_ub + (size_t)M_PAD * 1024;   // M_PAD*1024 (alias hnb)
  unsigned short* buf_hnb = buf_yb;                          // M_PAD*512 (hn dead before scan)
  unsigned short* buf_wib = buf_yb + (size_t)M_PAD * 1024;   // 2048*512 (in_W; head_W after loop)
  unsigned short* buf_wob = buf_wib + (size_t)2048 * 512;    // 512*1024 (out_W)
  unsigned short* buf_wxb = buf_wob + (size_t)512 * 1024;    // 128*1024 (xproj_W padded)

  dim3 blk(256);

  k_embed<<<(M_ROWS * D_MODEL + 255) / 256, blk, 0, stream>>>(x, embed_W, embed_b, buf_h);

  for (int i = 0; i < NB_LAYERS; ++i) {
    // weights -> bf16 (per layer); xproj_W zero-padded 64->128 rows
    k_f2b<<<(2048 * 512 + 255) / 256, blk, 0, stream>>>(
        in_W + (size_t)i * 2048 * D_MODEL, buf_wib, 2048 * 512, 2048 * 512);
    k_f2b<<<(512 * 1024 + 255) / 256, blk, 0, stream>>>(
        out_W + (size_t)i * D_MODEL * D_INNER, buf_wob, 512 * 1024, 512 * 1024);
    k_f2b<<<(128 * 1024 + 255) / 256, blk, 0, stream>>>(
        xproj_W + (size_t)i * 64 * D_INNER, buf_wxb, 64 * 1024, 128 * 1024);

    // residual update + layernorm -> hn (bf16)
    k_resid_norm<<<(M_ROWS + 3) / 4, blk, 0, stream>>>(
        buf_h, buf_res, nullptr, buf_hnb, norm_w + i * D_MODEL, norm_b + i * D_MODEL,
        i > 0 ? 1 : 0, 0);

    // in_proj (bf16 MFMA): xz = hn @ in_W^T   (M, 2048)
    k_gemm_mfma<<<dim3(2048 / 128, M_PAD / 128), blk, 0, stream>>>(
        buf_hnb, buf_wib, buf_xz, 2048, M_ROWS, 2048, 512);

    // conv + silu -> u (bf16)
    k_conv_silu<<<(M_ROWS * D_INNER + 255) / 256, blk, 0, stream>>>(
        buf_xz, conv_w + (size_t)i * D_INNER * D_CONV, conv_b + (size_t)i * D_INNER, buf_ub);

    // x_proj (bf16 MFMA): xdbl = u @ xproj_W^T   (M, 64), N padded to 128
    k_gemm_mfma<<<dim3(1, M_PAD / 128), blk, 0, stream>>>(
        buf_ub, buf_wxb, buf_xdbl, 64, M_ROWS, 64, 1024);

    // dt_proj + softplus (fp32) -> cols [0,1024) of xz; ldc=2048
    k_gemm_tn<1><<<dim3(D_INNER / TILE, M_ROWS / TILE), blk, 0, stream>>>(
        buf_xdbl, 64, dtproj_W + (size_t)i * D_INNER * DT_RANK, dtproj_b + (size_t)i * D_INNER,
        buf_xz, 2048, D_INNER, DT_RANK);

    // selective scan -> y (bf16, overwrites hn region; hn is dead)
    k_scan<<<dim3(BATCH, D_INNER / 256), blk, 0, stream>>>(
        buf_xz, buf_ub, buf_xdbl, A_log + (size_t)i * D_INNER * D_STATE,
        Dskip + (size_t)i * D_INNER, buf_yb);

    // out_proj (bf16 MFMA): h = y @ out_W^T   (M, 512)
    k_gemm_mfma<<<dim3(512 / 128, M_PAD / 128), blk, 0, stream>>>(
        buf_yb, buf_wob, buf_h, 512, M_ROWS, 512, 1024);
  }

  // final residual + rmsnorm -> xf (bf16, over hnb region; y dead)
  k_resid_norm<<<(M_ROWS + 3) / 4, blk, 0, stream>>>(
      buf_h, buf_res, nullptr, buf_hnb, normf_w, normf_b, 1, 1);

  // head_W -> bf16 padded to 256 rows (reuse in_W bf16 buffer — dead after last in_proj)
  k_f2b<<<(256 * 512 + 255) / 256, blk, 0, stream>>>(head_W, buf_wib, CITY * 512, 256 * 512);

  // head (bf16 MFMA): logits = xf @ head_W^T   (M, 200), N padded to 256
  k_gemm_mfma<<<dim3(256 / 128, M_PAD / 128), blk, 0, stream>>>(
      buf_hnb, buf_wib, out, CITY, M_ROWS, CITY, 512);
}